// Round 8
// baseline (1265.053 us; speedup 1.0000x reference)
//
#include <hip/hip_runtime.h>
#include <hip/hip_cooperative_groups.h>
#include <math.h>

namespace cg = cooperative_groups;

#define NN 32768      // nodes
#define EE 524288     // edges
#define CC 128        // in channels
#define CTWO 256      // 2C
#define ACTE 262143   // active edges: (i+1) < E*(1-0.5)
#define NBUK 262144   // sort buckets (2^18)

// output offsets (floats)
#define OFF_NEWX   0
#define OFF_SCORE  4194304
#define OFF_CSCORE 4718592
#define OFF_NEI    4751360
#define OFF_NBATCH 5799936
#define OFF_CLUST  5832704
#define OFF_NUMC   5865472

#define ALOADI(p)   __hip_atomic_load((p), __ATOMIC_RELAXED, __HIP_MEMORY_SCOPE_AGENT)
#define ASTOREI(p,v) __hip_atomic_store((p),(v), __ATOMIC_RELAXED, __HIP_MEMORY_SCOPE_AGENT)

// ---------------- init: replaces all memsets ----------------
__global__ __launch_bounds__(256) void k_init(unsigned* __restrict__ cnt,
                                              unsigned* __restrict__ curb,
                                              unsigned* __restrict__ sel,
                                              unsigned* __restrict__ dead,
                                              unsigned* __restrict__ best0,
                                              unsigned* __restrict__ best1,
                                              int* __restrict__ counts) {
    int g = blockIdx.x * 256 + threadIdx.x;
    cnt[g] = 0u;
    curb[g] = 0u;
    sel[g] = 0u;
    if (g < NN) { dead[g] = 0u; best0[g] = 0xFFFFFFFFu; best1[g] = 0xFFFFFFFFu; }
    if (g == 0) { counts[0] = ACTE; counts[1] = 0; }
}

// ---------------- GEMM1 (fp32): A[u]=W2_L*x_u, B[u]=W2_R*x_u + b2 ----------------
__global__ __launch_bounds__(256) void k_gemm1(const float* __restrict__ x,
                                               const float* __restrict__ W2,
                                               const float* __restrict__ b2,
                                               float* __restrict__ Abuf,
                                               float* __restrict__ Bbuf) {
    __shared__ float xs[32][36];
    __shared__ float wsh[32][260];
    const int t = threadIdx.x;
    const int jt = (t & 31) * 4;    // cols jt..jt+3 and jt+128..jt+131
    const int ty = t >> 5;
    const int nBase = blockIdx.x * 32;
    const int half = blockIdx.y;
    const float* W2base = W2 + (size_t)half * CC;

    float acc[4][8];
#pragma unroll
    for (int ni = 0; ni < 4; ni++)
#pragma unroll
        for (int m = 0; m < 8; m++)
            acc[ni][m] = (half == 1) ? b2[(m < 4 ? jt + m : jt + 124 + m)] : 0.0f;

    for (int kc = 0; kc < 4; ++kc) {
        const int kcBase = kc * 32;
        {
            int n = t >> 3, k0 = (t & 7) * 4;
            const float4 v = *(const float4*)&x[(size_t)(nBase + n) * CC + kcBase + k0];
            *(float4*)&xs[n][k0] = v;
        }
        {
            int k = t & 31, j0 = t >> 5;
#pragma unroll
            for (int i = 0; i < 32; i++) {
                int j = j0 + 8 * i;
                wsh[k][j] = W2base[(size_t)j * CTWO + kcBase + k];
            }
        }
        __syncthreads();
#pragma unroll 4
        for (int k = 0; k < 32; k++) {
            const float4 w0 = *(const float4*)&wsh[k][jt];
            const float4 w1 = *(const float4*)&wsh[k][jt + 128];
            float wv[8] = {w0.x, w0.y, w0.z, w0.w, w1.x, w1.y, w1.z, w1.w};
            float xv[4];
#pragma unroll
            for (int ni = 0; ni < 4; ni++) xv[ni] = xs[ty * 4 + ni][k];
#pragma unroll
            for (int ni = 0; ni < 4; ni++)
#pragma unroll
                for (int m = 0; m < 8; m++) acc[ni][m] = fmaf(xv[ni], wv[m], acc[ni][m]);
        }
        __syncthreads();
    }
    float* outb = (half == 0) ? Abuf : Bbuf;
#pragma unroll
    for (int ni = 0; ni < 4; ni++) {
        size_t u = (size_t)(nBase + ty * 4 + ni);
        *(float4*)&outb[u * CTWO + jt]       = make_float4(acc[ni][0], acc[ni][1], acc[ni][2], acc[ni][3]);
        *(float4*)&outb[u * CTWO + jt + 128] = make_float4(acc[ni][4], acc[ni][5], acc[ni][6], acc[ni][7]);
    }
}

// ---------------- bucket key ----------------
__device__ __forceinline__ int bucket_of(float s) {
    int b = (NBUK - 1) - (int)(s * (float)NBUK);
    if (b < 0) b = 0;
    if (b > NBUK - 1) b = NBUK - 1;
    return b;
}

// ---------------- edge scoring (fp32) + fused bucket count ----------------
__global__ __launch_bounds__(256) void k_edge_score(const float* __restrict__ Abuf,
                                                    const float* __restrict__ Bbuf,
                                                    const int* __restrict__ src,
                                                    const int* __restrict__ dst,
                                                    const float* __restrict__ W1,
                                                    const float* __restrict__ b1,
                                                    float* __restrict__ scoreOut,
                                                    unsigned* __restrict__ cnt) {
    const int wave = threadIdx.x >> 6, lane = threadIdx.x & 63;
    const int e = blockIdx.x * 4 + wave;
    const int s = src[e], t = dst[e];
    const float4 a = *(const float4*)&Abuf[(size_t)s * CTWO + lane * 4];
    const float4 b = *(const float4*)&Bbuf[(size_t)t * CTWO + lane * 4];
    const float4 w = *(const float4*)&W1[lane * 4];
    float z = 0.0f, pre;
    pre = a.x + b.x; z = fmaf(w.x, pre > 0.0f ? pre : 0.0f, z);
    pre = a.y + b.y; z = fmaf(w.y, pre > 0.0f ? pre : 0.0f, z);
    pre = a.z + b.z; z = fmaf(w.z, pre > 0.0f ? pre : 0.0f, z);
    pre = a.w + b.w; z = fmaf(w.w, pre > 0.0f ? pre : 0.0f, z);
    for (int off = 32; off > 0; off >>= 1) z += __shfl_down(z, off);
    if (lane == 0) {
        z += b1[0];
        float sg = 1.0f / (1.0f + expf(-z));
        scoreOut[e] = sg;
        atomicAdd(&cnt[bucket_of(sg)], 1u);
    }
}

// ---------------- parallel exclusive scan of cnt[NBUK] -> offs ----------------
__global__ __launch_bounds__(256) void k_offs_partA(const unsigned* __restrict__ cnt,
                                                    unsigned* __restrict__ bsum) {
    int g = blockIdx.x * 256 + threadIdx.x;
    unsigned v = cnt[g];
#pragma unroll
    for (int off = 32; off > 0; off >>= 1) v += __shfl_down(v, off);
    __shared__ unsigned ws[4];
    int lane = threadIdx.x & 63, wave = threadIdx.x >> 6;
    if (lane == 0) ws[wave] = v;
    __syncthreads();
    if (threadIdx.x == 0) bsum[blockIdx.x] = ws[0] + ws[1] + ws[2] + ws[3];
}

__global__ __launch_bounds__(1024) void k_scan1024(const unsigned* __restrict__ bsum,
                                                   unsigned* __restrict__ boffs) {
    __shared__ unsigned s[1024];
    int t = threadIdx.x;
    unsigned v = bsum[t];
    s[t] = v;
    __syncthreads();
    for (int off = 1; off < 1024; off <<= 1) {
        unsigned u = (t >= off) ? s[t - off] : 0u;
        __syncthreads();
        s[t] += u;
        __syncthreads();
    }
    boffs[t] = s[t] - v;
}

__global__ __launch_bounds__(256) void k_offs_partC(const unsigned* __restrict__ cnt,
                                                    const unsigned* __restrict__ boffs,
                                                    unsigned* __restrict__ offs) {
    __shared__ unsigned s[256];
    int t = threadIdx.x;
    int g = blockIdx.x * 256 + t;
    unsigned v = cnt[g];
    s[t] = v;
    __syncthreads();
    for (int off = 1; off < 256; off <<= 1) {
        unsigned u = (t >= off) ? s[t - off] : 0u;
        __syncthreads();
        s[t] += u;
        __syncthreads();
    }
    offs[g] = boffs[blockIdx.x] + s[t] - v;
}

// ---------------- scatter packed tuples {src,dst,score_bits,e} ----------------
__global__ void k_scatter(const float* __restrict__ score32, const int* __restrict__ src,
                          const int* __restrict__ dst, const unsigned* __restrict__ offs,
                          unsigned* __restrict__ curb, uint4* __restrict__ pack) {
    int e = blockIdx.x * blockDim.x + threadIdx.x;
    if (e >= EE) return;
    float sc = score32[e];
    int b = bucket_of(sc);
    unsigned p = offs[b] + atomicAdd(&curb[b], 1u);
    pack[p] = make_uint4((unsigned)src[e], (unsigned)dst[e], __float_as_uint(sc), (unsigned)e);
}

// in-place selection sort per bucket by (score desc, e asc)
__global__ void k_bucket_sort(const unsigned* __restrict__ cnt, const unsigned* __restrict__ offs,
                              uint4* __restrict__ pack) {
    int b = blockIdx.x * blockDim.x + threadIdx.x;
    if (b >= NBUK) return;
    int n = (int)cnt[b];
    if (n <= 1) return;
    unsigned o = offs[b];
    for (int i = 0; i < n - 1; i++) {
        int bi = i;
        uint4 bv = pack[o + i];
        float bs = __uint_as_float(bv.z);
        for (int j = i + 1; j < n; j++) {
            uint4 cv = pack[o + j];
            float cs = __uint_as_float(cv.z);
            if (cs > bs || (cs == bs && cv.w < bv.w)) { bi = j; bv = cv; bs = cs; }
        }
        if (bi != i) { pack[o + bi] = pack[o + i]; pack[o + i] = bv; }
    }
}

// ---------------- cooperative handshake matching: ALL rounds in one kernel ----------------
__global__ __launch_bounds__(256) void k_match(const uint4* __restrict__ pack,
                                               unsigned* __restrict__ list0,
                                               unsigned* __restrict__ list1,
                                               int* __restrict__ counts,
                                               unsigned* __restrict__ best0,
                                               unsigned* __restrict__ best1,
                                               unsigned* __restrict__ dead,
                                               unsigned* __restrict__ sel) {
    cg::grid_group grid = cg::this_grid();
    const unsigned gid = blockIdx.x * blockDim.x + threadIdx.x;
    const unsigned gsz = gridDim.x * blockDim.x;
    int cur = 0;
    int round = 0;
    while (true) {
        const int n = ALOADI(&counts[cur]);
        if (n == 0) break;
        if (gid == 0) ASTOREI(&counts[1 - cur], 0);
        unsigned* Lc = cur ? list1 : list0;
        unsigned* Ln = cur ? list0 : list1;
        unsigned* bc = cur ? best1 : best0;
        unsigned* bo = cur ? best0 : best1;
        // P1: alive edges bid for both endpoints; reset the other best array
        for (unsigned i = gid; i < (unsigned)n; i += gsz) {
            unsigned r = (round == 0) ? i : Lc[i];
            uint4 pk = pack[r];
            int s = (int)pk.x, t = (int)pk.y;
            if (!ALOADI(&dead[s]) && !ALOADI(&dead[t])) {
                atomicMin(&bc[s], r);
                atomicMin(&bc[t], r);
            }
        }
        for (unsigned u = gid; u < NN; u += gsz) bo[u] = 0xFFFFFFFFu;
        grid.sync();
        // P2: select locally-dominant edges, kill endpoints, compact survivors
        for (unsigned i = gid; i < (unsigned)n; i += gsz) {
            unsigned r = (round == 0) ? i : Lc[i];
            uint4 pk = pack[r];
            int s = (int)pk.x, t = (int)pk.y;
            if (ALOADI(&dead[s]) || ALOADI(&dead[t])) continue;
            if (ALOADI(&bc[s]) == r && ALOADI(&bc[t]) == r) {
                sel[r] = 1u;
                ASTOREI(&dead[s], 1u);
                ASTOREI(&dead[t], 1u);
            } else {
                int p = atomicAdd(&counts[1 - cur], 1);
                Ln[p] = r;
            }
        }
        grid.sync();
        cur ^= 1;
        round++;
    }
}

// ---------------- fused epilogue scans ----------------
__global__ __launch_bounds__(256) void k_part2(const unsigned* __restrict__ sel,
                                               const unsigned* __restrict__ dead,
                                               unsigned* __restrict__ selBsum,
                                               unsigned* __restrict__ survBsum,
                                               float* __restrict__ cscore,
                                               float* __restrict__ nbatch) {
    int bid = blockIdx.x;
    __shared__ unsigned ws[4];
    int lane = threadIdx.x & 63, wave = threadIdx.x >> 6;
    if (bid < 1024) {
        int r = bid * 256 + threadIdx.x;
        unsigned f = (r < ACTE) ? sel[r] : 0u;
        unsigned long long m = __ballot(f != 0u);
        if (lane == 0) ws[wave] = (unsigned)__popcll(m);
        __syncthreads();
        if (threadIdx.x == 0) selBsum[bid] = ws[0] + ws[1] + ws[2] + ws[3];
    } else {
        int u = (bid - 1024) * 256 + threadIdx.x;
        cscore[u] = 100.0f;
        nbatch[u] = 0.0f;
        unsigned f = (dead[u] == 0u) ? 1u : 0u;
        unsigned long long m = __ballot(f != 0u);
        if (lane == 0) ws[wave] = (unsigned)__popcll(m);
        __syncthreads();
        if (threadIdx.x == 0) survBsum[bid - 1024] = ws[0] + ws[1] + ws[2] + ws[3];
    }
}

__global__ __launch_bounds__(1024) void k_scan2(const unsigned* __restrict__ selBsum,
                                                const unsigned* __restrict__ survBsum,
                                                unsigned* __restrict__ selBoff,
                                                unsigned* __restrict__ survBoff,
                                                int* __restrict__ scalars,
                                                float* __restrict__ numcOut) {
    __shared__ unsigned s[1024];
    __shared__ unsigned Msh;
    int t = threadIdx.x;
    unsigned v = selBsum[t];
    s[t] = v;
    __syncthreads();
    for (int off = 1; off < 1024; off <<= 1) {
        unsigned u = (t >= off) ? s[t - off] : 0u;
        __syncthreads();
        s[t] += u;
        __syncthreads();
    }
    selBoff[t] = s[t] - v;
    if (t == 1023) Msh = s[1023];
    __syncthreads();
    unsigned v2 = (t < 128) ? survBsum[t] : 0u;
    s[t] = v2;
    __syncthreads();
    for (int off = 1; off < 128; off <<= 1) {
        unsigned u = (t >= off && t < 128) ? s[t - off] : 0u;
        __syncthreads();
        if (t < 128) s[t] += u;
        __syncthreads();
    }
    if (t < 128) survBoff[t] = s[t] - v2;
    if (t == 127) {
        int M = (int)Msh;
        int numc = M + (int)s[127];
        scalars[0] = M;
        scalars[1] = numc;
        numcOut[0] = (float)numc;
    }
}

__global__ __launch_bounds__(256) void k_write2(const unsigned* __restrict__ sel,
                                                const unsigned* __restrict__ dead,
                                                const unsigned* __restrict__ selBoff,
                                                const unsigned* __restrict__ survBoff,
                                                const uint4* __restrict__ pack,
                                                int* __restrict__ cluster,
                                                int* __restrict__ mergeS,
                                                int* __restrict__ mergeT,
                                                int* __restrict__ survN,
                                                float* __restrict__ cscoreOut,
                                                const int* __restrict__ scalars) {
    int bid = blockIdx.x;
    __shared__ unsigned ws[4];
    int lane = threadIdx.x & 63, wave = threadIdx.x >> 6;
    if (bid < 1024) {
        int r = bid * 256 + threadIdx.x;
        unsigned f = (r < ACTE) ? sel[r] : 0u;
        unsigned long long m = __ballot(f != 0u);
        if (lane == 0) ws[wave] = (unsigned)__popcll(m);
        __syncthreads();
        if (f) {
            unsigned woff = 0;
            for (int i = 0; i < wave; i++) woff += ws[i];
            unsigned prefix = (unsigned)__popcll(m & ((1ull << lane) - 1ull));
            int i0 = (int)(selBoff[bid] + woff + prefix);
            uint4 pk = pack[r];
            int s_ = (int)pk.x, t_ = (int)pk.y;
            cluster[s_] = i0;
            cluster[t_] = i0;
            mergeS[i0] = s_;
            mergeT[i0] = t_;
            cscoreOut[i0] = __uint_as_float(pk.z);
        }
    } else {
        int u = (bid - 1024) * 256 + threadIdx.x;
        unsigned f = (dead[u] == 0u) ? 1u : 0u;
        unsigned long long m = __ballot(f != 0u);
        if (lane == 0) ws[wave] = (unsigned)__popcll(m);
        __syncthreads();
        if (f) {
            unsigned woff = 0;
            for (int i = 0; i < wave; i++) woff += ws[i];
            unsigned prefix = (unsigned)__popcll(m & ((1ull << lane) - 1ull));
            int idx = (int)(survBoff[bid - 1024] + woff + prefix);
            const int M = scalars[0];
            cluster[u] = M + idx;
            survN[idx] = u;
        }
    }
}

// ---------------- fused newx + final ----------------
__global__ void k_newx_final(const float* __restrict__ x, const int* __restrict__ mergeS,
                             const int* __restrict__ mergeT, const int* __restrict__ survN,
                             const int* __restrict__ scalars, const int* __restrict__ ei,
                             const int* __restrict__ batch, const int* __restrict__ cluster,
                             float* __restrict__ outx, float* __restrict__ neiOut,
                             float* __restrict__ nbatch, float* __restrict__ clusterOut) {
    int gidx = blockIdx.x * blockDim.x + threadIdx.x;
    int c = gidx >> 7;
    int j = gidx & 127;
    const int M = scalars[0], numc = scalars[1];
    float v = 0.0f;
    if (c < M) {
        int s = mergeS[c], t = mergeT[c];
        v = x[s * CC + j] + (s != t ? x[t * CC + j] : 0.0f);
    } else if (c < numc) {
        int u = survN[c - M];
        v = x[u * CC + j];
    }
    outx[gidx] = v;
    if (gidx < 2 * EE) neiOut[gidx] = (float)cluster[ei[gidx]];
    if (gidx < NN) {
        clusterOut[gidx] = (float)cluster[gidx];
        nbatch[cluster[gidx]] = (float)batch[gidx];
    }
}

// ---------------- host ----------------
extern "C" void kernel_launch(void* const* d_in, const int* in_sizes, int n_in,
                              void* d_out, int out_size, void* d_ws, size_t ws_size,
                              hipStream_t stream) {
    const float* x  = (const float*)d_in[0];
    const float* W2 = (const float*)d_in[2];
    const float* b2 = (const float*)d_in[3];
    const float* W1 = (const float*)d_in[4];
    const float* b1 = (const float*)d_in[5];
    const int* ei   = (const int*)d_in[6];
    const int* bat  = (const int*)d_in[7];
    const int* src = ei;
    const int* dst = ei + EE;
    float* out = (float*)d_out;
    float* score32 = out + OFF_SCORE;

    char* p = (char*)d_ws;
    auto take = [&](size_t bytes) -> char* {
        char* r = p;
        p += (bytes + 255) & ~(size_t)255;
        return r;
    };
    float*    Abuf    = (float*)take((size_t)NN * CTWO * 4);
    float*    Bbuf    = (float*)take((size_t)NN * CTWO * 4);
    unsigned* cnt     = (unsigned*)take((size_t)NBUK * 4);
    unsigned* offs    = (unsigned*)take((size_t)NBUK * 4);
    unsigned* curb    = (unsigned*)take((size_t)NBUK * 4);
    uint4*    pack    = (uint4*)take((size_t)EE * 16);
    unsigned* list0   = (unsigned*)take((size_t)NBUK * 4);
    unsigned* list1   = (unsigned*)take((size_t)NBUK * 4);
    unsigned* best0   = (unsigned*)take((size_t)NN * 4);
    unsigned* best1   = (unsigned*)take((size_t)NN * 4);
    unsigned* dead    = (unsigned*)take((size_t)NN * 4);
    unsigned* sel     = (unsigned*)take((size_t)NBUK * 4);
    int*      cluster = (int*)take((size_t)NN * 4);
    int*      mergeS  = (int*)take((size_t)NN * 4);
    int*      mergeT  = (int*)take((size_t)NN * 4);
    int*      survN   = (int*)take((size_t)NN * 4);
    unsigned* offsBsum= (unsigned*)take(1024 * 4);
    unsigned* offsBoff= (unsigned*)take(1024 * 4);
    unsigned* selBsum = (unsigned*)take(1024 * 4);
    unsigned* selBoff = (unsigned*)take(1024 * 4);
    unsigned* survBsum= (unsigned*)take(128 * 4);
    unsigned* survBoff= (unsigned*)take(128 * 4);
    int*      counts  = (int*)take(256);
    int*      scalars = (int*)take(256);

    k_init<<<NBUK / 256, 256, 0, stream>>>(cnt, curb, sel, dead, best0, best1, counts);
    k_gemm1<<<dim3(NN / 32, 2), 256, 0, stream>>>(x, W2, b2, Abuf, Bbuf);
    k_edge_score<<<EE / 4, 256, 0, stream>>>(Abuf, Bbuf, src, dst, W1, b1, score32, cnt);
    k_offs_partA<<<NBUK / 256, 256, 0, stream>>>(cnt, offsBsum);
    k_scan1024<<<1, 1024, 0, stream>>>(offsBsum, offsBoff);
    k_offs_partC<<<NBUK / 256, 256, 0, stream>>>(cnt, offsBoff, offs);
    k_scatter<<<EE / 256, 256, 0, stream>>>(score32, src, dst, offs, curb, pack);
    k_bucket_sort<<<NBUK / 256, 256, 0, stream>>>(cnt, offs, pack);

    // cooperative matching: all rounds in one launch (256 blocks -> 1 block/CU, co-resident)
    {
        const uint4* packC = pack;
        void* args[] = {(void*)&packC, (void*)&list0, (void*)&list1, (void*)&counts,
                        (void*)&best0, (void*)&best1, (void*)&dead, (void*)&sel};
        hipLaunchCooperativeKernel((const void*)k_match, dim3(256), dim3(256), args, 0, stream);
    }

    k_part2<<<1152, 256, 0, stream>>>(sel, dead, selBsum, survBsum, out + OFF_CSCORE,
                                      out + OFF_NBATCH);
    k_scan2<<<1, 1024, 0, stream>>>(selBsum, survBsum, selBoff, survBoff, scalars,
                                    out + OFF_NUMC);
    k_write2<<<1152, 256, 0, stream>>>(sel, dead, selBoff, survBoff, pack, cluster, mergeS,
                                       mergeT, survN, out + OFF_CSCORE, scalars);
    k_newx_final<<<(NN * CC) / 256, 256, 0, stream>>>(x, mergeS, mergeT, survN, scalars, ei, bat,
                                                      cluster, out + OFF_NEWX, out + OFF_NEI,
                                                      out + OFF_NBATCH, out + OFF_CLUST);
}

// Round 9
// 888.333 us; speedup vs baseline: 1.4241x; 1.4241x over previous
//
#include <hip/hip_runtime.h>
#include <math.h>

#define NN 32768      // nodes
#define EE 524288     // edges
#define CC 128        // in channels
#define CTWO 256      // 2C
#define ACTE 262143   // active edges: (i+1) < E*(1-0.5)
#define NBUK 262144   // sort buckets (2^18)

// output offsets (floats)
#define OFF_NEWX   0
#define OFF_SCORE  4194304
#define OFF_CSCORE 4718592
#define OFF_NEI    4751360
#define OFF_NBATCH 5799936
#define OFF_CLUST  5832704
#define OFF_NUMC   5865472

#define ALOADI(p)   __hip_atomic_load((p), __ATOMIC_RELAXED, __HIP_MEMORY_SCOPE_AGENT)
#define ASTOREI(p,v) __hip_atomic_store((p),(v), __ATOMIC_RELAXED, __HIP_MEMORY_SCOPE_AGENT)

// ---------------- init: replaces all memsets ----------------
__global__ __launch_bounds__(256) void k_init(unsigned* __restrict__ cnt,
                                              unsigned* __restrict__ curb,
                                              unsigned* __restrict__ sel,
                                              unsigned* __restrict__ dead,
                                              unsigned* __restrict__ best0,
                                              unsigned* __restrict__ best1,
                                              int* __restrict__ counts) {
    int g = blockIdx.x * 256 + threadIdx.x;
    cnt[g] = 0u;
    curb[g] = 0u;
    sel[g] = 0u;
    if (g < NN) { dead[g] = 0u; best0[g] = 0xFFFFFFFFu; best1[g] = 0xFFFFFFFFu; }
    if (g == 0) { counts[0] = ACTE; counts[1] = 0; }
}

// ---------------- GEMM1 (fp32): A[u]=W2_L*x_u, B[u]=W2_R*x_u + b2 ----------------
__global__ __launch_bounds__(256) void k_gemm1(const float* __restrict__ x,
                                               const float* __restrict__ W2,
                                               const float* __restrict__ b2,
                                               float* __restrict__ Abuf,
                                               float* __restrict__ Bbuf) {
    __shared__ float xs[32][36];
    __shared__ float wsh[32][260];
    const int t = threadIdx.x;
    const int jt = (t & 31) * 4;    // cols jt..jt+3 and jt+128..jt+131
    const int ty = t >> 5;
    const int nBase = blockIdx.x * 32;
    const int half = blockIdx.y;
    const float* W2base = W2 + (size_t)half * CC;

    float acc[4][8];
#pragma unroll
    for (int ni = 0; ni < 4; ni++)
#pragma unroll
        for (int m = 0; m < 8; m++)
            acc[ni][m] = (half == 1) ? b2[(m < 4 ? jt + m : jt + 124 + m)] : 0.0f;

    for (int kc = 0; kc < 4; ++kc) {
        const int kcBase = kc * 32;
        {
            int n = t >> 3, k0 = (t & 7) * 4;
            const float4 v = *(const float4*)&x[(size_t)(nBase + n) * CC + kcBase + k0];
            *(float4*)&xs[n][k0] = v;
        }
        {
            int k = t & 31, j0 = t >> 5;
#pragma unroll
            for (int i = 0; i < 32; i++) {
                int j = j0 + 8 * i;
                wsh[k][j] = W2base[(size_t)j * CTWO + kcBase + k];
            }
        }
        __syncthreads();
#pragma unroll 4
        for (int k = 0; k < 32; k++) {
            const float4 w0 = *(const float4*)&wsh[k][jt];
            const float4 w1 = *(const float4*)&wsh[k][jt + 128];
            float wv[8] = {w0.x, w0.y, w0.z, w0.w, w1.x, w1.y, w1.z, w1.w};
            float xv[4];
#pragma unroll
            for (int ni = 0; ni < 4; ni++) xv[ni] = xs[ty * 4 + ni][k];
#pragma unroll
            for (int ni = 0; ni < 4; ni++)
#pragma unroll
                for (int m = 0; m < 8; m++) acc[ni][m] = fmaf(xv[ni], wv[m], acc[ni][m]);
        }
        __syncthreads();
    }
    float* outb = (half == 0) ? Abuf : Bbuf;
#pragma unroll
    for (int ni = 0; ni < 4; ni++) {
        size_t u = (size_t)(nBase + ty * 4 + ni);
        *(float4*)&outb[u * CTWO + jt]       = make_float4(acc[ni][0], acc[ni][1], acc[ni][2], acc[ni][3]);
        *(float4*)&outb[u * CTWO + jt + 128] = make_float4(acc[ni][4], acc[ni][5], acc[ni][6], acc[ni][7]);
    }
}

// ---------------- bucket key ----------------
__device__ __forceinline__ int bucket_of(float s) {
    int b = (NBUK - 1) - (int)(s * (float)NBUK);
    if (b < 0) b = 0;
    if (b > NBUK - 1) b = NBUK - 1;
    return b;
}

// ---------------- edge scoring (fp32) + fused bucket count ----------------
__global__ __launch_bounds__(256) void k_edge_score(const float* __restrict__ Abuf,
                                                    const float* __restrict__ Bbuf,
                                                    const int* __restrict__ src,
                                                    const int* __restrict__ dst,
                                                    const float* __restrict__ W1,
                                                    const float* __restrict__ b1,
                                                    float* __restrict__ scoreOut,
                                                    unsigned* __restrict__ cnt) {
    const int wave = threadIdx.x >> 6, lane = threadIdx.x & 63;
    const int e = blockIdx.x * 4 + wave;
    const int s = src[e], t = dst[e];
    const float4 a = *(const float4*)&Abuf[(size_t)s * CTWO + lane * 4];
    const float4 b = *(const float4*)&Bbuf[(size_t)t * CTWO + lane * 4];
    const float4 w = *(const float4*)&W1[lane * 4];
    float z = 0.0f, pre;
    pre = a.x + b.x; z = fmaf(w.x, pre > 0.0f ? pre : 0.0f, z);
    pre = a.y + b.y; z = fmaf(w.y, pre > 0.0f ? pre : 0.0f, z);
    pre = a.z + b.z; z = fmaf(w.z, pre > 0.0f ? pre : 0.0f, z);
    pre = a.w + b.w; z = fmaf(w.w, pre > 0.0f ? pre : 0.0f, z);
    for (int off = 32; off > 0; off >>= 1) z += __shfl_down(z, off);
    if (lane == 0) {
        z += b1[0];
        float sg = 1.0f / (1.0f + expf(-z));
        scoreOut[e] = sg;
        atomicAdd(&cnt[bucket_of(sg)], 1u);
    }
}

// ---------------- parallel exclusive scan of cnt[NBUK] -> offs ----------------
__global__ __launch_bounds__(256) void k_offs_partA(const unsigned* __restrict__ cnt,
                                                    unsigned* __restrict__ bsum) {
    int g = blockIdx.x * 256 + threadIdx.x;
    unsigned v = cnt[g];
#pragma unroll
    for (int off = 32; off > 0; off >>= 1) v += __shfl_down(v, off);
    __shared__ unsigned ws[4];
    int lane = threadIdx.x & 63, wave = threadIdx.x >> 6;
    if (lane == 0) ws[wave] = v;
    __syncthreads();
    if (threadIdx.x == 0) bsum[blockIdx.x] = ws[0] + ws[1] + ws[2] + ws[3];
}

__global__ __launch_bounds__(1024) void k_scan1024(const unsigned* __restrict__ bsum,
                                                   unsigned* __restrict__ boffs) {
    __shared__ unsigned s[1024];
    int t = threadIdx.x;
    unsigned v = bsum[t];
    s[t] = v;
    __syncthreads();
    for (int off = 1; off < 1024; off <<= 1) {
        unsigned u = (t >= off) ? s[t - off] : 0u;
        __syncthreads();
        s[t] += u;
        __syncthreads();
    }
    boffs[t] = s[t] - v;
}

__global__ __launch_bounds__(256) void k_offs_partC(const unsigned* __restrict__ cnt,
                                                    const unsigned* __restrict__ boffs,
                                                    unsigned* __restrict__ offs) {
    __shared__ unsigned s[256];
    int t = threadIdx.x;
    int g = blockIdx.x * 256 + t;
    unsigned v = cnt[g];
    s[t] = v;
    __syncthreads();
    for (int off = 1; off < 256; off <<= 1) {
        unsigned u = (t >= off) ? s[t - off] : 0u;
        __syncthreads();
        s[t] += u;
        __syncthreads();
    }
    offs[g] = boffs[blockIdx.x] + s[t] - v;
}

// ---------------- scatter packed tuples {src,dst,score_bits,e} ----------------
__global__ void k_scatter(const float* __restrict__ score32, const int* __restrict__ src,
                          const int* __restrict__ dst, const unsigned* __restrict__ offs,
                          unsigned* __restrict__ curb, uint4* __restrict__ pack) {
    int e = blockIdx.x * blockDim.x + threadIdx.x;
    if (e >= EE) return;
    float sc = score32[e];
    int b = bucket_of(sc);
    unsigned p = offs[b] + atomicAdd(&curb[b], 1u);
    pack[p] = make_uint4((unsigned)src[e], (unsigned)dst[e], __float_as_uint(sc), (unsigned)e);
}

// in-place selection sort per bucket by (score desc, e asc)
__global__ void k_bucket_sort(const unsigned* __restrict__ cnt, const unsigned* __restrict__ offs,
                              uint4* __restrict__ pack) {
    int b = blockIdx.x * blockDim.x + threadIdx.x;
    if (b >= NBUK) return;
    int n = (int)cnt[b];
    if (n <= 1) return;
    unsigned o = offs[b];
    for (int i = 0; i < n - 1; i++) {
        int bi = i;
        uint4 bv = pack[o + i];
        float bs = __uint_as_float(bv.z);
        for (int j = i + 1; j < n; j++) {
            uint4 cv = pack[o + j];
            float cs = __uint_as_float(cv.z);
            if (cs > bs || (cs == bs && cv.w < bv.w)) { bi = j; bv = cv; bs = cs; }
        }
        if (bi != i) { pack[o + bi] = pack[o + i]; pack[o + i] = bv; }
    }
}

// ---------------- handshake matching ----------------
// P1: alive edges bid (atomicMin rank) at both endpoints. NO NN-sweep.
__global__ void k_mp1(const uint4* __restrict__ pack, const unsigned* __restrict__ Lc,
                      int* __restrict__ counts, int cur, unsigned* __restrict__ bc,
                      const unsigned* __restrict__ dead, int isFirst) {
    const unsigned gid = blockIdx.x * blockDim.x + threadIdx.x;
    const unsigned gsz = gridDim.x * blockDim.x;
    const int n = counts[cur];
    if (gid == 0) counts[1 - cur] = 0;
    for (unsigned i = gid; i < (unsigned)n; i += gsz) {
        unsigned r = isFirst ? i : Lc[i];
        uint4 pk = pack[r];
        int s = (int)pk.x, t = (int)pk.y;
        if (!dead[s] && !dead[t]) { atomicMin(&bc[s], r); atomicMin(&bc[t], r); }
    }
}

// P2: select locally-dominant; survivors reset the *other* best buffer for their endpoints
// (exactly the nodes that can be bid next round), replacing the NN-wide sweep.
__global__ void k_mp2(const uint4* __restrict__ pack, const unsigned* __restrict__ Lc,
                      unsigned* __restrict__ Ln, int* __restrict__ counts, int cur,
                      const unsigned* __restrict__ bc, unsigned* __restrict__ bo,
                      unsigned* __restrict__ dead, unsigned* __restrict__ sel, int isFirst) {
    const unsigned gid = blockIdx.x * blockDim.x + threadIdx.x;
    const unsigned gsz = gridDim.x * blockDim.x;
    const int n = counts[cur];
    for (unsigned i = gid; i < (unsigned)n; i += gsz) {
        unsigned r = isFirst ? i : Lc[i];
        uint4 pk = pack[r];
        int s = (int)pk.x, t = (int)pk.y;
        if (ALOADI(&dead[s]) || ALOADI(&dead[t])) continue;
        if (bc[s] == r && bc[t] == r) {
            sel[r] = 1u;
            ASTOREI(&dead[s], 1u);
            ASTOREI(&dead[t], 1u);
        } else {
            int p = atomicAdd(&counts[1 - cur], 1);
            Ln[p] = r;
            bo[s] = 0xFFFFFFFFu;
            bo[t] = 0xFFFFFFFFu;
        }
    }
}

// single-block tail: loops rounds until empty; per-round cost O(n), no NN sweep
__global__ __launch_bounds__(1024) void k_mtail(const uint4* __restrict__ pack,
                                                unsigned* __restrict__ listA,
                                                unsigned* __restrict__ listB,
                                                int* __restrict__ counts, int cur0,
                                                unsigned* __restrict__ best0,
                                                unsigned* __restrict__ best1,
                                                unsigned* __restrict__ dead,
                                                unsigned* __restrict__ sel) {
    const int tid = threadIdx.x, tsz = blockDim.x;
    int cur = cur0;
    while (true) {
        int n = ALOADI(&counts[cur]);
        if (tid == 0) ASTOREI(&counts[1 - cur], 0);
        __syncthreads();
        if (n == 0) break;
        unsigned* Lc = cur ? listB : listA;
        unsigned* Ln = cur ? listA : listB;
        unsigned* bc = cur ? best1 : best0;
        unsigned* bo = cur ? best0 : best1;
        for (int i = tid; i < n; i += tsz) {
            unsigned r = Lc[i];
            uint4 pk = pack[r];
            int s = (int)pk.x, t = (int)pk.y;
            if (!dead[s] && !dead[t]) { atomicMin(&bc[s], r); atomicMin(&bc[t], r); }
        }
        __syncthreads();
        for (int i = tid; i < n; i += tsz) {
            unsigned r = Lc[i];
            uint4 pk = pack[r];
            int s = (int)pk.x, t = (int)pk.y;
            if (dead[s] || dead[t]) continue;
            unsigned bs_ = ALOADI(&bc[s]);
            unsigned bt_ = ALOADI(&bc[t]);
            if (bs_ == r && bt_ == r) {
                sel[r] = 1u;
                dead[s] = 1u;
                dead[t] = 1u;
            } else {
                int p = atomicAdd(&counts[1 - cur], 1);
                Ln[p] = r;
                bo[s] = 0xFFFFFFFFu;
                bo[t] = 0xFFFFFFFFu;
            }
        }
        __syncthreads();
        cur ^= 1;
    }
}

// ---------------- fused epilogue scans ----------------
__global__ __launch_bounds__(256) void k_part2(const unsigned* __restrict__ sel,
                                               const unsigned* __restrict__ dead,
                                               unsigned* __restrict__ selBsum,
                                               unsigned* __restrict__ survBsum,
                                               float* __restrict__ cscore,
                                               float* __restrict__ nbatch) {
    int bid = blockIdx.x;
    __shared__ unsigned ws[4];
    int lane = threadIdx.x & 63, wave = threadIdx.x >> 6;
    if (bid < 1024) {
        int r = bid * 256 + threadIdx.x;
        unsigned f = (r < ACTE) ? sel[r] : 0u;
        unsigned long long m = __ballot(f != 0u);
        if (lane == 0) ws[wave] = (unsigned)__popcll(m);
        __syncthreads();
        if (threadIdx.x == 0) selBsum[bid] = ws[0] + ws[1] + ws[2] + ws[3];
    } else {
        int u = (bid - 1024) * 256 + threadIdx.x;
        cscore[u] = 100.0f;
        nbatch[u] = 0.0f;
        unsigned f = (dead[u] == 0u) ? 1u : 0u;
        unsigned long long m = __ballot(f != 0u);
        if (lane == 0) ws[wave] = (unsigned)__popcll(m);
        __syncthreads();
        if (threadIdx.x == 0) survBsum[bid - 1024] = ws[0] + ws[1] + ws[2] + ws[3];
    }
}

__global__ __launch_bounds__(1024) void k_scan2(const unsigned* __restrict__ selBsum,
                                                const unsigned* __restrict__ survBsum,
                                                unsigned* __restrict__ selBoff,
                                                unsigned* __restrict__ survBoff,
                                                int* __restrict__ scalars,
                                                float* __restrict__ numcOut) {
    __shared__ unsigned s[1024];
    __shared__ unsigned Msh;
    int t = threadIdx.x;
    unsigned v = selBsum[t];
    s[t] = v;
    __syncthreads();
    for (int off = 1; off < 1024; off <<= 1) {
        unsigned u = (t >= off) ? s[t - off] : 0u;
        __syncthreads();
        s[t] += u;
        __syncthreads();
    }
    selBoff[t] = s[t] - v;
    if (t == 1023) Msh = s[1023];
    __syncthreads();
    unsigned v2 = (t < 128) ? survBsum[t] : 0u;
    s[t] = v2;
    __syncthreads();
    for (int off = 1; off < 128; off <<= 1) {
        unsigned u = (t >= off && t < 128) ? s[t - off] : 0u;
        __syncthreads();
        if (t < 128) s[t] += u;
        __syncthreads();
    }
    if (t < 128) survBoff[t] = s[t] - v2;
    if (t == 127) {
        int M = (int)Msh;
        int numc = M + (int)s[127];
        scalars[0] = M;
        scalars[1] = numc;
        numcOut[0] = (float)numc;
    }
}

__global__ __launch_bounds__(256) void k_write2(const unsigned* __restrict__ sel,
                                                const unsigned* __restrict__ dead,
                                                const unsigned* __restrict__ selBoff,
                                                const unsigned* __restrict__ survBoff,
                                                const uint4* __restrict__ pack,
                                                int* __restrict__ cluster,
                                                int* __restrict__ mergeS,
                                                int* __restrict__ mergeT,
                                                int* __restrict__ survN,
                                                float* __restrict__ cscoreOut,
                                                const int* __restrict__ scalars) {
    int bid = blockIdx.x;
    __shared__ unsigned ws[4];
    int lane = threadIdx.x & 63, wave = threadIdx.x >> 6;
    if (bid < 1024) {
        int r = bid * 256 + threadIdx.x;
        unsigned f = (r < ACTE) ? sel[r] : 0u;
        unsigned long long m = __ballot(f != 0u);
        if (lane == 0) ws[wave] = (unsigned)__popcll(m);
        __syncthreads();
        if (f) {
            unsigned woff = 0;
            for (int i = 0; i < wave; i++) woff += ws[i];
            unsigned prefix = (unsigned)__popcll(m & ((1ull << lane) - 1ull));
            int i0 = (int)(selBoff[bid] + woff + prefix);
            uint4 pk = pack[r];
            int s_ = (int)pk.x, t_ = (int)pk.y;
            cluster[s_] = i0;
            cluster[t_] = i0;
            mergeS[i0] = s_;
            mergeT[i0] = t_;
            cscoreOut[i0] = __uint_as_float(pk.z);
        }
    } else {
        int u = (bid - 1024) * 256 + threadIdx.x;
        unsigned f = (dead[u] == 0u) ? 1u : 0u;
        unsigned long long m = __ballot(f != 0u);
        if (lane == 0) ws[wave] = (unsigned)__popcll(m);
        __syncthreads();
        if (f) {
            unsigned woff = 0;
            for (int i = 0; i < wave; i++) woff += ws[i];
            unsigned prefix = (unsigned)__popcll(m & ((1ull << lane) - 1ull));
            int idx = (int)(survBoff[bid - 1024] + woff + prefix);
            const int M = scalars[0];
            cluster[u] = M + idx;
            survN[idx] = u;
        }
    }
}

// ---------------- fused newx + final ----------------
__global__ void k_newx_final(const float* __restrict__ x, const int* __restrict__ mergeS,
                             const int* __restrict__ mergeT, const int* __restrict__ survN,
                             const int* __restrict__ scalars, const int* __restrict__ ei,
                             const int* __restrict__ batch, const int* __restrict__ cluster,
                             float* __restrict__ outx, float* __restrict__ neiOut,
                             float* __restrict__ nbatch, float* __restrict__ clusterOut) {
    int gidx = blockIdx.x * blockDim.x + threadIdx.x;
    int c = gidx >> 7;
    int j = gidx & 127;
    const int M = scalars[0], numc = scalars[1];
    float v = 0.0f;
    if (c < M) {
        int s = mergeS[c], t = mergeT[c];
        v = x[s * CC + j] + (s != t ? x[t * CC + j] : 0.0f);
    } else if (c < numc) {
        int u = survN[c - M];
        v = x[u * CC + j];
    }
    outx[gidx] = v;
    if (gidx < 2 * EE) neiOut[gidx] = (float)cluster[ei[gidx]];
    if (gidx < NN) {
        clusterOut[gidx] = (float)cluster[gidx];
        nbatch[cluster[gidx]] = (float)batch[gidx];
    }
}

// ---------------- host ----------------
extern "C" void kernel_launch(void* const* d_in, const int* in_sizes, int n_in,
                              void* d_out, int out_size, void* d_ws, size_t ws_size,
                              hipStream_t stream) {
    const float* x  = (const float*)d_in[0];
    const float* W2 = (const float*)d_in[2];
    const float* b2 = (const float*)d_in[3];
    const float* W1 = (const float*)d_in[4];
    const float* b1 = (const float*)d_in[5];
    const int* ei   = (const int*)d_in[6];
    const int* bat  = (const int*)d_in[7];
    const int* src = ei;
    const int* dst = ei + EE;
    float* out = (float*)d_out;
    float* score32 = out + OFF_SCORE;

    char* p = (char*)d_ws;
    auto take = [&](size_t bytes) -> char* {
        char* r = p;
        p += (bytes + 255) & ~(size_t)255;
        return r;
    };
    float*    Abuf    = (float*)take((size_t)NN * CTWO * 4);
    float*    Bbuf    = (float*)take((size_t)NN * CTWO * 4);
    unsigned* cnt     = (unsigned*)take((size_t)NBUK * 4);
    unsigned* offs    = (unsigned*)take((size_t)NBUK * 4);
    unsigned* curb    = (unsigned*)take((size_t)NBUK * 4);
    uint4*    pack    = (uint4*)take((size_t)EE * 16);
    unsigned* list0   = (unsigned*)take((size_t)NBUK * 4);
    unsigned* list1   = (unsigned*)take((size_t)NBUK * 4);
    unsigned* best0   = (unsigned*)take((size_t)NN * 4);
    unsigned* best1   = (unsigned*)take((size_t)NN * 4);
    unsigned* dead    = (unsigned*)take((size_t)NN * 4);
    unsigned* sel     = (unsigned*)take((size_t)NBUK * 4);
    int*      cluster = (int*)take((size_t)NN * 4);
    int*      mergeS  = (int*)take((size_t)NN * 4);
    int*      mergeT  = (int*)take((size_t)NN * 4);
    int*      survN   = (int*)take((size_t)NN * 4);
    unsigned* offsBsum= (unsigned*)take(1024 * 4);
    unsigned* offsBoff= (unsigned*)take(1024 * 4);
    unsigned* selBsum = (unsigned*)take(1024 * 4);
    unsigned* selBoff = (unsigned*)take(1024 * 4);
    unsigned* survBsum= (unsigned*)take(128 * 4);
    unsigned* survBoff= (unsigned*)take(128 * 4);
    int*      counts  = (int*)take(256);
    int*      scalars = (int*)take(256);

    k_init<<<NBUK / 256, 256, 0, stream>>>(cnt, curb, sel, dead, best0, best1, counts);
    k_gemm1<<<dim3(NN / 32, 2), 256, 0, stream>>>(x, W2, b2, Abuf, Bbuf);
    k_edge_score<<<EE / 4, 256, 0, stream>>>(Abuf, Bbuf, src, dst, W1, b1, score32, cnt);
    k_offs_partA<<<NBUK / 256, 256, 0, stream>>>(cnt, offsBsum);
    k_scan1024<<<1, 1024, 0, stream>>>(offsBsum, offsBoff);
    k_offs_partC<<<NBUK / 256, 256, 0, stream>>>(cnt, offsBoff, offs);
    k_scatter<<<EE / 256, 256, 0, stream>>>(score32, src, dst, offs, curb, pack);
    k_bucket_sort<<<NBUK / 256, 256, 0, stream>>>(cnt, offs, pack);

    const int NBIG = 5;
    for (int r = 0; r < NBIG; ++r) {
        int cur = r & 1;
        int isFirst = (r == 0) ? 1 : 0;
        unsigned* Lc = cur ? list1 : list0;
        unsigned* Ln = cur ? list0 : list1;
        unsigned* bc = cur ? best1 : best0;
        unsigned* bo = cur ? best0 : best1;
        k_mp1<<<1024, 256, 0, stream>>>(pack, Lc, counts, cur, bc, dead, isFirst);
        k_mp2<<<1024, 256, 0, stream>>>(pack, Lc, Ln, counts, cur, bc, bo, dead, sel, isFirst);
    }
    k_mtail<<<1, 1024, 0, stream>>>(pack, list0, list1, counts, NBIG & 1, best0, best1,
                                    dead, sel);

    k_part2<<<1152, 256, 0, stream>>>(sel, dead, selBsum, survBsum, out + OFF_CSCORE,
                                      out + OFF_NBATCH);
    k_scan2<<<1, 1024, 0, stream>>>(selBsum, survBsum, selBoff, survBoff, scalars,
                                    out + OFF_NUMC);
    k_write2<<<1152, 256, 0, stream>>>(sel, dead, selBoff, survBoff, pack, cluster, mergeS,
                                       mergeT, survN, out + OFF_CSCORE, scalars);
    k_newx_final<<<(NN * CC) / 256, 256, 0, stream>>>(x, mergeS, mergeT, survN, scalars, ei, bat,
                                                      cluster, out + OFF_NEWX, out + OFF_NEI,
                                                      out + OFF_NBATCH, out + OFF_CLUST);
}

// Round 10
// 706.443 us; speedup vs baseline: 1.7907x; 1.2575x over previous
//
#include <hip/hip_runtime.h>
#include <math.h>

#define NN 32768      // nodes
#define EE 524288     // edges
#define CC 128        // in channels
#define CTWO 256      // 2C
#define ACTE 262143   // active edges: (i+1) < E*(1-0.5)
#define NBUK 262144   // sort buckets (2^18)

#define TCAP 3072     // LDS tail capacity (edges)
#define NCAP 6144     // LDS tail node capacity (2*TCAP)

// output offsets (floats)
#define OFF_NEWX   0
#define OFF_SCORE  4194304
#define OFF_CSCORE 4718592
#define OFF_NEI    4751360
#define OFF_NBATCH 5799936
#define OFF_CLUST  5832704
#define OFF_NUMC   5865472

#define ALOADI(p)   __hip_atomic_load((p), __ATOMIC_RELAXED, __HIP_MEMORY_SCOPE_AGENT)
#define ASTOREI(p,v) __hip_atomic_store((p),(v), __ATOMIC_RELAXED, __HIP_MEMORY_SCOPE_AGENT)

// ---------------- init: replaces all memsets ----------------
__global__ __launch_bounds__(256) void k_init(unsigned* __restrict__ cnt,
                                              unsigned* __restrict__ curb,
                                              unsigned* __restrict__ sel,
                                              unsigned* __restrict__ dead,
                                              unsigned* __restrict__ best0,
                                              unsigned* __restrict__ best1,
                                              int* __restrict__ nodeMap,
                                              int* __restrict__ counts) {
    int g = blockIdx.x * 256 + threadIdx.x;
    cnt[g] = 0u;
    curb[g] = 0u;
    sel[g] = 0u;
    if (g < NN) {
        dead[g] = 0u;
        best0[g] = 0xFFFFFFFFu;
        best1[g] = 0xFFFFFFFFu;
        nodeMap[g] = -1;
    }
    if (g == 0) { counts[0] = ACTE; counts[1] = 0; }
}

// ---------------- GEMM1 (fp32): A[u]=W2_L*x_u, B[u]=W2_R*x_u + b2 ----------------
__global__ __launch_bounds__(256) void k_gemm1(const float* __restrict__ x,
                                               const float* __restrict__ W2,
                                               const float* __restrict__ b2,
                                               float* __restrict__ Abuf,
                                               float* __restrict__ Bbuf) {
    __shared__ float xs[32][36];
    __shared__ float wsh[32][260];
    const int t = threadIdx.x;
    const int jt = (t & 31) * 4;    // cols jt..jt+3 and jt+128..jt+131
    const int ty = t >> 5;
    const int nBase = blockIdx.x * 32;
    const int half = blockIdx.y;
    const float* W2base = W2 + (size_t)half * CC;

    float acc[4][8];
#pragma unroll
    for (int ni = 0; ni < 4; ni++)
#pragma unroll
        for (int m = 0; m < 8; m++)
            acc[ni][m] = (half == 1) ? b2[(m < 4 ? jt + m : jt + 124 + m)] : 0.0f;

    for (int kc = 0; kc < 4; ++kc) {
        const int kcBase = kc * 32;
        {
            int n = t >> 3, k0 = (t & 7) * 4;
            const float4 v = *(const float4*)&x[(size_t)(nBase + n) * CC + kcBase + k0];
            *(float4*)&xs[n][k0] = v;
        }
        {
            int k = t & 31, j0 = t >> 5;
#pragma unroll
            for (int i = 0; i < 32; i++) {
                int j = j0 + 8 * i;
                wsh[k][j] = W2base[(size_t)j * CTWO + kcBase + k];
            }
        }
        __syncthreads();
#pragma unroll 4
        for (int k = 0; k < 32; k++) {
            const float4 w0 = *(const float4*)&wsh[k][jt];
            const float4 w1 = *(const float4*)&wsh[k][jt + 128];
            float wv[8] = {w0.x, w0.y, w0.z, w0.w, w1.x, w1.y, w1.z, w1.w};
            float xv[4];
#pragma unroll
            for (int ni = 0; ni < 4; ni++) xv[ni] = xs[ty * 4 + ni][k];
#pragma unroll
            for (int ni = 0; ni < 4; ni++)
#pragma unroll
                for (int m = 0; m < 8; m++) acc[ni][m] = fmaf(xv[ni], wv[m], acc[ni][m]);
        }
        __syncthreads();
    }
    float* outb = (half == 0) ? Abuf : Bbuf;
#pragma unroll
    for (int ni = 0; ni < 4; ni++) {
        size_t u = (size_t)(nBase + ty * 4 + ni);
        *(float4*)&outb[u * CTWO + jt]       = make_float4(acc[ni][0], acc[ni][1], acc[ni][2], acc[ni][3]);
        *(float4*)&outb[u * CTWO + jt + 128] = make_float4(acc[ni][4], acc[ni][5], acc[ni][6], acc[ni][7]);
    }
}

// ---------------- bucket key ----------------
__device__ __forceinline__ int bucket_of(float s) {
    int b = (NBUK - 1) - (int)(s * (float)NBUK);
    if (b < 0) b = 0;
    if (b > NBUK - 1) b = NBUK - 1;
    return b;
}

// ---------------- edge scoring (fp32) + fused bucket count ----------------
__global__ __launch_bounds__(256) void k_edge_score(const float* __restrict__ Abuf,
                                                    const float* __restrict__ Bbuf,
                                                    const int* __restrict__ src,
                                                    const int* __restrict__ dst,
                                                    const float* __restrict__ W1,
                                                    const float* __restrict__ b1,
                                                    float* __restrict__ scoreOut,
                                                    unsigned* __restrict__ cnt) {
    const int wave = threadIdx.x >> 6, lane = threadIdx.x & 63;
    const int e = blockIdx.x * 4 + wave;
    const int s = src[e], t = dst[e];
    const float4 a = *(const float4*)&Abuf[(size_t)s * CTWO + lane * 4];
    const float4 b = *(const float4*)&Bbuf[(size_t)t * CTWO + lane * 4];
    const float4 w = *(const float4*)&W1[lane * 4];
    float z = 0.0f, pre;
    pre = a.x + b.x; z = fmaf(w.x, pre > 0.0f ? pre : 0.0f, z);
    pre = a.y + b.y; z = fmaf(w.y, pre > 0.0f ? pre : 0.0f, z);
    pre = a.z + b.z; z = fmaf(w.z, pre > 0.0f ? pre : 0.0f, z);
    pre = a.w + b.w; z = fmaf(w.w, pre > 0.0f ? pre : 0.0f, z);
    for (int off = 32; off > 0; off >>= 1) z += __shfl_down(z, off);
    if (lane == 0) {
        z += b1[0];
        float sg = 1.0f / (1.0f + expf(-z));
        scoreOut[e] = sg;
        atomicAdd(&cnt[bucket_of(sg)], 1u);
    }
}

// ---------------- parallel exclusive scan of cnt[NBUK] -> offs ----------------
__global__ __launch_bounds__(256) void k_offs_partA(const unsigned* __restrict__ cnt,
                                                    unsigned* __restrict__ bsum) {
    int g = blockIdx.x * 256 + threadIdx.x;
    unsigned v = cnt[g];
#pragma unroll
    for (int off = 32; off > 0; off >>= 1) v += __shfl_down(v, off);
    __shared__ unsigned ws[4];
    int lane = threadIdx.x & 63, wave = threadIdx.x >> 6;
    if (lane == 0) ws[wave] = v;
    __syncthreads();
    if (threadIdx.x == 0) bsum[blockIdx.x] = ws[0] + ws[1] + ws[2] + ws[3];
}

__global__ __launch_bounds__(1024) void k_scan1024(const unsigned* __restrict__ bsum,
                                                   unsigned* __restrict__ boffs) {
    __shared__ unsigned s[1024];
    int t = threadIdx.x;
    unsigned v = bsum[t];
    s[t] = v;
    __syncthreads();
    for (int off = 1; off < 1024; off <<= 1) {
        unsigned u = (t >= off) ? s[t - off] : 0u;
        __syncthreads();
        s[t] += u;
        __syncthreads();
    }
    boffs[t] = s[t] - v;
}

__global__ __launch_bounds__(256) void k_offs_partC(const unsigned* __restrict__ cnt,
                                                    const unsigned* __restrict__ boffs,
                                                    unsigned* __restrict__ offs) {
    __shared__ unsigned s[256];
    int t = threadIdx.x;
    int g = blockIdx.x * 256 + t;
    unsigned v = cnt[g];
    s[t] = v;
    __syncthreads();
    for (int off = 1; off < 256; off <<= 1) {
        unsigned u = (t >= off) ? s[t - off] : 0u;
        __syncthreads();
        s[t] += u;
        __syncthreads();
    }
    offs[g] = boffs[blockIdx.x] + s[t] - v;
}

// ---------------- scatter packed tuples {src,dst,score_bits,e} ----------------
__global__ void k_scatter(const float* __restrict__ score32, const int* __restrict__ src,
                          const int* __restrict__ dst, const unsigned* __restrict__ offs,
                          unsigned* __restrict__ curb, uint4* __restrict__ pack) {
    int e = blockIdx.x * blockDim.x + threadIdx.x;
    if (e >= EE) return;
    float sc = score32[e];
    int b = bucket_of(sc);
    unsigned p = offs[b] + atomicAdd(&curb[b], 1u);
    pack[p] = make_uint4((unsigned)src[e], (unsigned)dst[e], __float_as_uint(sc), (unsigned)e);
}

// in-place selection sort per bucket by (score desc, e asc)
__global__ void k_bucket_sort(const unsigned* __restrict__ cnt, const unsigned* __restrict__ offs,
                              uint4* __restrict__ pack) {
    int b = blockIdx.x * blockDim.x + threadIdx.x;
    if (b >= NBUK) return;
    int n = (int)cnt[b];
    if (n <= 1) return;
    unsigned o = offs[b];
    for (int i = 0; i < n - 1; i++) {
        int bi = i;
        uint4 bv = pack[o + i];
        float bs = __uint_as_float(bv.z);
        for (int j = i + 1; j < n; j++) {
            uint4 cv = pack[o + j];
            float cs = __uint_as_float(cv.z);
            if (cs > bs || (cs == bs && cv.w < bv.w)) { bi = j; bv = cv; bs = cs; }
        }
        if (bi != i) { pack[o + bi] = pack[o + i]; pack[o + i] = bv; }
    }
}

// ---------------- handshake matching (big rounds, R7-proven shape) ----------------
__global__ void k_mp1(const uint4* __restrict__ pack, const unsigned* __restrict__ Lc,
                      int* __restrict__ counts, int cur, unsigned* __restrict__ bc,
                      unsigned* __restrict__ bo, const unsigned* __restrict__ dead,
                      int isFirst) {
    const unsigned gid = blockIdx.x * blockDim.x + threadIdx.x;
    const unsigned gsz = gridDim.x * blockDim.x;
    const int n = counts[cur];
    if (gid == 0) counts[1 - cur] = 0;
    for (unsigned i = gid; i < (unsigned)n; i += gsz) {
        unsigned r = isFirst ? i : Lc[i];
        uint4 pk = pack[r];
        int s = (int)pk.x, t = (int)pk.y;
        if (!dead[s] && !dead[t]) { atomicMin(&bc[s], r); atomicMin(&bc[t], r); }
    }
    for (unsigned u = gid; u < NN; u += gsz) bo[u] = 0xFFFFFFFFu;
}

__global__ void k_mp2(const uint4* __restrict__ pack, const unsigned* __restrict__ Lc,
                      unsigned* __restrict__ Ln, int* __restrict__ counts, int cur,
                      const unsigned* __restrict__ bc, unsigned* __restrict__ dead,
                      unsigned* __restrict__ sel, int isFirst) {
    const unsigned gid = blockIdx.x * blockDim.x + threadIdx.x;
    const unsigned gsz = gridDim.x * blockDim.x;
    const int n = counts[cur];
    for (unsigned i = gid; i < (unsigned)n; i += gsz) {
        unsigned r = isFirst ? i : Lc[i];
        uint4 pk = pack[r];
        int s = (int)pk.x, t = (int)pk.y;
        if (ALOADI(&dead[s]) || ALOADI(&dead[t])) continue;
        if (bc[s] == r && bc[t] == r) {
            sel[r] = 1u;
            ASTOREI(&dead[s], 1u);
            ASTOREI(&dead[t], 1u);
        } else {
            int p = atomicAdd(&counts[1 - cur], 1);
            Ln[p] = r;
        }
    }
}

// ---------------- tail: global fallback rounds, then all-LDS rounds ----------------
__global__ __launch_bounds__(1024) void k_mtail(const uint4* __restrict__ pack,
                                                unsigned* __restrict__ listA,
                                                unsigned* __restrict__ listB,
                                                int* __restrict__ counts, int cur0,
                                                unsigned* __restrict__ best0,
                                                unsigned* __restrict__ best1,
                                                unsigned* __restrict__ dead,
                                                unsigned* __restrict__ sel,
                                                int* __restrict__ nodeMap) {
    const int tid = threadIdx.x, tsz = 1024;
    int cur = cur0;
    // ---- fallback: global-memory rounds until list fits LDS ----
    while (true) {
        int n = ALOADI(&counts[cur]);
        if (n <= TCAP) break;
        if (tid == 0) ASTOREI(&counts[1 - cur], 0);
        __syncthreads();
        unsigned* Lc = cur ? listB : listA;
        unsigned* Ln = cur ? listA : listB;
        unsigned* bc = cur ? best1 : best0;
        unsigned* bo = cur ? best0 : best1;
        for (int i = tid; i < n; i += tsz) {
            unsigned r = Lc[i];
            uint4 pk = pack[r];
            int s = (int)pk.x, t = (int)pk.y;
            if (!dead[s] && !dead[t]) { atomicMin(&bc[s], r); atomicMin(&bc[t], r); }
        }
        __syncthreads();
        for (int i = tid; i < n; i += tsz) {
            unsigned r = Lc[i];
            uint4 pk = pack[r];
            int s = (int)pk.x, t = (int)pk.y;
            if (dead[s] || dead[t]) continue;
            unsigned bs_ = ALOADI(&bc[s]);
            unsigned bt_ = ALOADI(&bc[t]);
            if (bs_ == r && bt_ == r) {
                sel[r] = 1u;
                dead[s] = 1u;
                dead[t] = 1u;
            } else {
                int p = atomicAdd(&counts[1 - cur], 1);
                Ln[p] = r;
                bo[s] = 0xFFFFFFFFu;   // reset only possible future bidders
                bo[t] = 0xFFFFFFFFu;
            }
        }
        __syncthreads();
        cur ^= 1;
    }
    const int n0 = ALOADI(&counts[cur]);
    if (n0 == 0) return;
    const unsigned* Lc = cur ? listB : listA;

    // ---- LDS phase ----
    __shared__ unsigned stL[TCAP];          // compact (cs<<16)|ct  (orig during setup)
    __shared__ unsigned rnkL[TCAP];         // full rank
    __shared__ unsigned bestL[NCAP];        // rank bids per compact node
    __shared__ unsigned deadLb[NCAP / 32];  // compact dead bitmap
    __shared__ unsigned char aliveB[TCAP];
    __shared__ int nNodesSh, remainSh;
    if (tid == 0) { nNodesSh = 0; remainSh = n0; }
    for (int i = tid; i < NCAP / 32; i += tsz) deadLb[i] = 0u;
    __syncthreads();
    // pass 1: stage edges, claim compact node ids
    for (int i = tid; i < n0; i += tsz) {
        unsigned r = Lc[i];
        uint4 pk = pack[r];
        rnkL[i] = r;
        stL[i] = (pk.x << 16) | pk.y;   // original ids (15-bit, fits)
        aliveB[i] = 1;
        int us[2] = {(int)pk.x, (int)pk.y};
#pragma unroll
        for (int q = 0; q < 2; q++) {
            int u = us[q];
            int prev = atomicCAS(&nodeMap[u], -1, -2);
            if (prev == -1) {
                int cid = atomicAdd(&nNodesSh, 1);
                if (ALOADI(&dead[u])) atomicOr(&deadLb[cid >> 5], 1u << (cid & 31));
                ASTOREI(&nodeMap[u], cid);
            }
        }
    }
    __threadfence_block();
    __syncthreads();
    // pass 2: remap endpoints to compact ids
    for (int i = tid; i < n0; i += tsz) {
        unsigned st = stL[i];
        int cs = ALOADI(&nodeMap[(int)(st >> 16)]);
        int ct = ALOADI(&nodeMap[(int)(st & 0xFFFFu)]);
        stL[i] = ((unsigned)cs << 16) | (unsigned)ct;
    }
    __syncthreads();
    // rounds, fully LDS-resident
    while (true) {
        for (int i = tid; i < NCAP; i += tsz) bestL[i] = 0xFFFFFFFFu;
        __syncthreads();
        for (int i = tid; i < n0; i += tsz) {
            if (!aliveB[i]) continue;
            unsigned st = stL[i];
            int cs = (int)(st >> 16), ct = (int)(st & 0xFFFFu);
            unsigned ds = (deadLb[cs >> 5] >> (cs & 31)) & 1u;
            unsigned dt = (deadLb[ct >> 5] >> (ct & 31)) & 1u;
            if (ds | dt) { aliveB[i] = 0; atomicSub(&remainSh, 1); continue; }
            unsigned r = rnkL[i];
            atomicMin(&bestL[cs], r);
            atomicMin(&bestL[ct], r);
        }
        __syncthreads();
        for (int i = tid; i < n0; i += tsz) {
            if (!aliveB[i]) continue;
            unsigned st = stL[i];
            int cs = (int)(st >> 16), ct = (int)(st & 0xFFFFu);
            unsigned r = rnkL[i];
            if (bestL[cs] == r && bestL[ct] == r) {
                sel[r] = 1u;
                atomicOr(&deadLb[cs >> 5], 1u << (cs & 31));
                atomicOr(&deadLb[ct >> 5], 1u << (ct & 31));
                aliveB[i] = 0;
                atomicSub(&remainSh, 1);
            }
        }
        __syncthreads();
        if (remainSh == 0) break;
        __syncthreads();
    }
    // writeback: reflect LDS deaths in global dead[] for the epilogue
    for (int i = tid; i < n0; i += tsz) {
        unsigned r = rnkL[i];
        uint4 pk = pack[r];
        unsigned st = stL[i];
        int cs = (int)(st >> 16), ct = (int)(st & 0xFFFFu);
        if ((deadLb[cs >> 5] >> (cs & 31)) & 1u) ASTOREI(&dead[pk.x], 1u);
        if ((deadLb[ct >> 5] >> (ct & 31)) & 1u) ASTOREI(&dead[pk.y], 1u);
    }
}

// ---------------- fused epilogue scans ----------------
__global__ __launch_bounds__(256) void k_part2(const unsigned* __restrict__ sel,
                                               const unsigned* __restrict__ dead,
                                               unsigned* __restrict__ selBsum,
                                               unsigned* __restrict__ survBsum,
                                               float* __restrict__ cscore,
                                               float* __restrict__ nbatch) {
    int bid = blockIdx.x;
    __shared__ unsigned ws[4];
    int lane = threadIdx.x & 63, wave = threadIdx.x >> 6;
    if (bid < 1024) {
        int r = bid * 256 + threadIdx.x;
        unsigned f = (r < ACTE) ? sel[r] : 0u;
        unsigned long long m = __ballot(f != 0u);
        if (lane == 0) ws[wave] = (unsigned)__popcll(m);
        __syncthreads();
        if (threadIdx.x == 0) selBsum[bid] = ws[0] + ws[1] + ws[2] + ws[3];
    } else {
        int u = (bid - 1024) * 256 + threadIdx.x;
        cscore[u] = 100.0f;
        nbatch[u] = 0.0f;
        unsigned f = (dead[u] == 0u) ? 1u : 0u;
        unsigned long long m = __ballot(f != 0u);
        if (lane == 0) ws[wave] = (unsigned)__popcll(m);
        __syncthreads();
        if (threadIdx.x == 0) survBsum[bid - 1024] = ws[0] + ws[1] + ws[2] + ws[3];
    }
}

__global__ __launch_bounds__(1024) void k_scan2(const unsigned* __restrict__ selBsum,
                                                const unsigned* __restrict__ survBsum,
                                                unsigned* __restrict__ selBoff,
                                                unsigned* __restrict__ survBoff,
                                                int* __restrict__ scalars,
                                                float* __restrict__ numcOut) {
    __shared__ unsigned s[1024];
    __shared__ unsigned Msh;
    int t = threadIdx.x;
    unsigned v = selBsum[t];
    s[t] = v;
    __syncthreads();
    for (int off = 1; off < 1024; off <<= 1) {
        unsigned u = (t >= off) ? s[t - off] : 0u;
        __syncthreads();
        s[t] += u;
        __syncthreads();
    }
    selBoff[t] = s[t] - v;
    if (t == 1023) Msh = s[1023];
    __syncthreads();
    unsigned v2 = (t < 128) ? survBsum[t] : 0u;
    s[t] = v2;
    __syncthreads();
    for (int off = 1; off < 128; off <<= 1) {
        unsigned u = (t >= off && t < 128) ? s[t - off] : 0u;
        __syncthreads();
        if (t < 128) s[t] += u;
        __syncthreads();
    }
    if (t < 128) survBoff[t] = s[t] - v2;
    if (t == 127) {
        int M = (int)Msh;
        int numc = M + (int)s[127];
        scalars[0] = M;
        scalars[1] = numc;
        numcOut[0] = (float)numc;
    }
}

__global__ __launch_bounds__(256) void k_write2(const unsigned* __restrict__ sel,
                                                const unsigned* __restrict__ dead,
                                                const unsigned* __restrict__ selBoff,
                                                const unsigned* __restrict__ survBoff,
                                                const uint4* __restrict__ pack,
                                                int* __restrict__ cluster,
                                                int* __restrict__ mergeS,
                                                int* __restrict__ mergeT,
                                                int* __restrict__ survN,
                                                float* __restrict__ cscoreOut,
                                                const int* __restrict__ scalars) {
    int bid = blockIdx.x;
    __shared__ unsigned ws[4];
    int lane = threadIdx.x & 63, wave = threadIdx.x >> 6;
    if (bid < 1024) {
        int r = bid * 256 + threadIdx.x;
        unsigned f = (r < ACTE) ? sel[r] : 0u;
        unsigned long long m = __ballot(f != 0u);
        if (lane == 0) ws[wave] = (unsigned)__popcll(m);
        __syncthreads();
        if (f) {
            unsigned woff = 0;
            for (int i = 0; i < wave; i++) woff += ws[i];
            unsigned prefix = (unsigned)__popcll(m & ((1ull << lane) - 1ull));
            int i0 = (int)(selBoff[bid] + woff + prefix);
            uint4 pk = pack[r];
            int s_ = (int)pk.x, t_ = (int)pk.y;
            cluster[s_] = i0;
            cluster[t_] = i0;
            mergeS[i0] = s_;
            mergeT[i0] = t_;
            cscoreOut[i0] = __uint_as_float(pk.z);
        }
    } else {
        int u = (bid - 1024) * 256 + threadIdx.x;
        unsigned f = (dead[u] == 0u) ? 1u : 0u;
        unsigned long long m = __ballot(f != 0u);
        if (lane == 0) ws[wave] = (unsigned)__popcll(m);
        __syncthreads();
        if (f) {
            unsigned woff = 0;
            for (int i = 0; i < wave; i++) woff += ws[i];
            unsigned prefix = (unsigned)__popcll(m & ((1ull << lane) - 1ull));
            int idx = (int)(survBoff[bid - 1024] + woff + prefix);
            const int M = scalars[0];
            cluster[u] = M + idx;
            survN[idx] = u;
        }
    }
}

// ---------------- fused newx + final ----------------
__global__ void k_newx_final(const float* __restrict__ x, const int* __restrict__ mergeS,
                             const int* __restrict__ mergeT, const int* __restrict__ survN,
                             const int* __restrict__ scalars, const int* __restrict__ ei,
                             const int* __restrict__ batch, const int* __restrict__ cluster,
                             float* __restrict__ outx, float* __restrict__ neiOut,
                             float* __restrict__ nbatch, float* __restrict__ clusterOut) {
    int gidx = blockIdx.x * blockDim.x + threadIdx.x;
    int c = gidx >> 7;
    int j = gidx & 127;
    const int M = scalars[0], numc = scalars[1];
    float v = 0.0f;
    if (c < M) {
        int s = mergeS[c], t = mergeT[c];
        v = x[s * CC + j] + (s != t ? x[t * CC + j] : 0.0f);
    } else if (c < numc) {
        int u = survN[c - M];
        v = x[u * CC + j];
    }
    outx[gidx] = v;
    if (gidx < 2 * EE) neiOut[gidx] = (float)cluster[ei[gidx]];
    if (gidx < NN) {
        clusterOut[gidx] = (float)cluster[gidx];
        nbatch[cluster[gidx]] = (float)batch[gidx];
    }
}

// ---------------- host ----------------
extern "C" void kernel_launch(void* const* d_in, const int* in_sizes, int n_in,
                              void* d_out, int out_size, void* d_ws, size_t ws_size,
                              hipStream_t stream) {
    const float* x  = (const float*)d_in[0];
    const float* W2 = (const float*)d_in[2];
    const float* b2 = (const float*)d_in[3];
    const float* W1 = (const float*)d_in[4];
    const float* b1 = (const float*)d_in[5];
    const int* ei   = (const int*)d_in[6];
    const int* bat  = (const int*)d_in[7];
    const int* src = ei;
    const int* dst = ei + EE;
    float* out = (float*)d_out;
    float* score32 = out + OFF_SCORE;

    char* p = (char*)d_ws;
    auto take = [&](size_t bytes) -> char* {
        char* r = p;
        p += (bytes + 255) & ~(size_t)255;
        return r;
    };
    float*    Abuf    = (float*)take((size_t)NN * CTWO * 4);
    float*    Bbuf    = (float*)take((size_t)NN * CTWO * 4);
    unsigned* cnt     = (unsigned*)take((size_t)NBUK * 4);
    unsigned* offs    = (unsigned*)take((size_t)NBUK * 4);
    unsigned* curb    = (unsigned*)take((size_t)NBUK * 4);
    uint4*    pack    = (uint4*)take((size_t)EE * 16);
    unsigned* list0   = (unsigned*)take((size_t)NBUK * 4);
    unsigned* list1   = (unsigned*)take((size_t)NBUK * 4);
    unsigned* best0   = (unsigned*)take((size_t)NN * 4);
    unsigned* best1   = (unsigned*)take((size_t)NN * 4);
    unsigned* dead    = (unsigned*)take((size_t)NN * 4);
    unsigned* sel     = (unsigned*)take((size_t)NBUK * 4);
    int*      nodeMap = (int*)take((size_t)NN * 4);
    int*      cluster = (int*)take((size_t)NN * 4);
    int*      mergeS  = (int*)take((size_t)NN * 4);
    int*      mergeT  = (int*)take((size_t)NN * 4);
    int*      survN   = (int*)take((size_t)NN * 4);
    unsigned* offsBsum= (unsigned*)take(1024 * 4);
    unsigned* offsBoff= (unsigned*)take(1024 * 4);
    unsigned* selBsum = (unsigned*)take(1024 * 4);
    unsigned* selBoff = (unsigned*)take(1024 * 4);
    unsigned* survBsum= (unsigned*)take(128 * 4);
    unsigned* survBoff= (unsigned*)take(128 * 4);
    int*      counts  = (int*)take(256);
    int*      scalars = (int*)take(256);

    k_init<<<NBUK / 256, 256, 0, stream>>>(cnt, curb, sel, dead, best0, best1, nodeMap, counts);
    k_gemm1<<<dim3(NN / 32, 2), 256, 0, stream>>>(x, W2, b2, Abuf, Bbuf);
    k_edge_score<<<EE / 4, 256, 0, stream>>>(Abuf, Bbuf, src, dst, W1, b1, score32, cnt);
    k_offs_partA<<<NBUK / 256, 256, 0, stream>>>(cnt, offsBsum);
    k_scan1024<<<1, 1024, 0, stream>>>(offsBsum, offsBoff);
    k_offs_partC<<<NBUK / 256, 256, 0, stream>>>(cnt, offsBoff, offs);
    k_scatter<<<EE / 256, 256, 0, stream>>>(score32, src, dst, offs, curb, pack);
    k_bucket_sort<<<NBUK / 256, 256, 0, stream>>>(cnt, offs, pack);

    const int NBIG = 10;
    for (int r = 0; r < NBIG; ++r) {
        int cur = r & 1;
        int isFirst = (r == 0) ? 1 : 0;
        unsigned* Lc = cur ? list1 : list0;
        unsigned* Ln = cur ? list0 : list1;
        unsigned* bc = cur ? best1 : best0;
        unsigned* bo = cur ? best0 : best1;
        k_mp1<<<1024, 256, 0, stream>>>(pack, Lc, counts, cur, bc, bo, dead, isFirst);
        k_mp2<<<1024, 256, 0, stream>>>(pack, Lc, Ln, counts, cur, bc, dead, sel, isFirst);
    }
    k_mtail<<<1, 1024, 0, stream>>>(pack, list0, list1, counts, NBIG & 1, best0, best1,
                                    dead, sel, nodeMap);

    k_part2<<<1152, 256, 0, stream>>>(sel, dead, selBsum, survBsum, out + OFF_CSCORE,
                                      out + OFF_NBATCH);
    k_scan2<<<1, 1024, 0, stream>>>(selBsum, survBsum, selBoff, survBoff, scalars,
                                    out + OFF_NUMC);
    k_write2<<<1152, 256, 0, stream>>>(sel, dead, selBoff, survBoff, pack, cluster, mergeS,
                                       mergeT, survN, out + OFF_CSCORE, scalars);
    k_newx_final<<<(NN * CC) / 256, 256, 0, stream>>>(x, mergeS, mergeT, survN, scalars, ei, bat,
                                                      cluster, out + OFF_NEWX, out + OFF_NEI,
                                                      out + OFF_NBATCH, out + OFF_CLUST);
}